// Round 10
// baseline (168.539 us; speedup 1.0000x reference)
//
#include <hip/hip_runtime.h>

// out[n,k,y,x] = sum_c grid[n,k,c,y/16,x/16] * guidemap[n,c,y,x]
// N=2, K=C=32, H=W=1024, 64x64 tiles of 16x16 px.
//
// R10: sequential-plane streaming, all k in registers.
//  - WG = (slab=(n,by), xoct): 16 rows x 128 px, all 32 c in, all 32 k out.
//  - Wave = full 512B row segment: every guide load / out store is 512B
//    contiguous, sweeping sequential 4KB DRAM rows (R6's access shape)
//    with NO traffic multiplication (R6's kq-split read guide 8x).
//  - Thread = 2 px x 32 k: acc[32] float2 = 64 VGPR (R3-proven budget).
//  - 8 tile matrices (32 KB) in LDS [c][kq][tx][4k]; ds_read_b128 with
//    8-lane broadcast groups spanning all 32 banks: conflict-free.
//  - 1024 WGs, ALL co-resident (4/CU). slab=bid&127 -> slab s (and all its
//    8 xoct spans) on XCD s%8: per-XCD L2 streams whole rows.
//  - Ring-8 guide prefetch; single barrier after matrix staging.

namespace {
constexpr int K = 32, C = 32;
constexpr int W = 1024;
constexpr int HW = 1024 * 1024;
constexpr size_t GRDN = (size_t)K * C * 64 * 64;  // floats per image
}

typedef float v2f __attribute__((ext_vector_type(2)));
typedef float v4f __attribute__((ext_vector_type(4)));

__device__ __forceinline__ void gl_lds4(const float* src, float* dst) {
    __builtin_amdgcn_global_load_lds(
        (const __attribute__((address_space(1))) void*)src,
        (__attribute__((address_space(3))) void*)dst, 4, 0, 0);
}

__global__ __launch_bounds__(256, 4) void gridup_kernel(
    const float* __restrict__ grd,   // [N][K][C][64][64]
    const float* __restrict__ gm,    // [N][C][1024][1024]
    float* __restrict__ out)         // [N][K][1024][1024]
{
    // sM flat: [c][kq][tx][k2] -> fi = c*256 + kq*32 + tx*4 + k2 (floats)
    __shared__ float sM[8192];       // 32 KB

    const int bid  = blockIdx.x;     // 0..1023
    const int slab = bid & 127;      // (n,by); slab%8 selects XCD
    const int xoct = bid >> 7;       // 128-px column span
    const int n    = slab >> 6;
    const int by   = slab & 63;
    const int t    = threadIdx.x;    // 0..255
    const int w    = t >> 6;         // wave 0..3
    const int l    = t & 63;

    // ---- stage 8 tile matrices: 8192 dword gathers (grid read once)
    {
        const float* gbase = grd + (size_t)n * GRDN + by * 64 + xoct * 8;
        #pragma unroll
        for (int i = 0; i < 32; ++i) {
            const int e  = i * 256 + t;     // 0..8191
            const int c  = e >> 8;
            const int r  = e & 255;
            const int kq = r >> 5;
            const int tx = (r >> 2) & 7;
            const int k  = kq * 4 + (r & 3);
            gl_lds4(gbase + (size_t)(k * 32 + c) * 4096 + tx, sM + e);
        }
    }
    __syncthreads();   // only barrier in the kernel

    const int tx  = l >> 3;          // tile within oct (8 lanes per tile)
    const int px  = xoct * 128 + l * 2;
    const float* gmn = gm + (size_t)n * C * HW + px;
    float*       on  = out + (size_t)n * K * HW + px;
    const v4f* sM4 = reinterpret_cast<const v4f*>(sM);
    const int y0 = by * 16;

    #pragma unroll 1
    for (int rr = 0; rr < 4; ++rr) {         // each wave: rows rr*4 + w
        const size_t roff = (size_t)(y0 + rr * 4 + w) * W;
        const float* gp = gmn + roff;

        // ring-8 guide prefetch (512B contiguous per wave-load)
        v2f ring[8];
        #pragma unroll
        for (int j = 0; j < 8; ++j)
            ring[j] = *reinterpret_cast<const v2f*>(gp + (size_t)j * HW);

        v2f acc[32];
        #pragma unroll
        for (int k = 0; k < 32; ++k) acc[k] = (v2f)0.f;

        #pragma unroll 1
        for (int cb = 0; cb < 4; ++cb) {
            #pragma unroll
            for (int cj = 0; cj < 8; ++cj) {
                const int c = cb * 8 + cj;
                const v2f u = ring[cj];
                if (cb < 3)
                    ring[cj] = *reinterpret_cast<const v2f*>(
                        gp + (size_t)(c + 8) * HW);
                #pragma unroll
                for (int kq = 0; kq < 8; ++kq) {
                    // 8-lane broadcast groups, 128B span: conflict-free
                    const v4f m = sM4[c * 64 + kq * 8 + tx];
                    acc[kq * 4 + 0] += m.x * u;
                    acc[kq * 4 + 1] += m.y * u;
                    acc[kq * 4 + 2] += m.z * u;
                    acc[kq * 4 + 3] += m.w * u;
                }
            }
        }

        // ---- stores: 32 x 512B contiguous per wave
        #pragma unroll
        for (int k = 0; k < 32; ++k)
            *reinterpret_cast<v2f*>(on + (size_t)k * HW + roff) = acc[k];
    }
}

extern "C" void kernel_launch(void* const* d_in, const int* in_sizes, int n_in,
                              void* d_out, int out_size, void* d_ws, size_t ws_size,
                              hipStream_t stream) {
    const float* grd = (const float*)d_in[0];   // grid:     2*32*32*64*64
    const float* gm  = (const float*)d_in[1];   // guidemap: 2*32*1024*1024
    float* out = (float*)d_out;                 // 2*32*1024*1024 fp32

    gridup_kernel<<<1024, 256, 0, stream>>>(grd, gm, out);
}